// Round 1
// baseline (1836.125 us; speedup 1.0000x reference)
//
#include <hip/hip_runtime.h>
#include <math.h>

// Problem constants (from setup_inputs: B=2, N=4096, T=2048, E=8192, MAX_DELAY=64)
static constexpr int NN = 4096;
static constexpr int TT = 2048;
static constexpr int EE = 8192;
static constexpr int BB = 2;
static constexpr int TK = 64;

// ---------------------------------------------------------------------------
// Kernel 1: per-node IRF  h[n,tau] = exp(-tau/kst)/kst, normalized over tau.
// One wave (64 lanes) per node; lane = tau.
// ---------------------------------------------------------------------------
__global__ void irf_kernel(const float* __restrict__ params, float* __restrict__ h) {
    int t = blockIdx.x * blockDim.x + threadIdx.x;
    int node = t >> 6, lane = t & 63;
    if (node >= NN) return;
    float p = params[node * 2];                               // col 0
    float sp = fmaxf(p, 0.f) + log1pf(expf(-fabsf(p)));       // stable softplus
    float kst = sp + 0.1f;
    float inv = 1.0f / kst;
    float hv = expf(-(float)lane * inv) * inv;
    float s = hv;
    #pragma unroll
    for (int d = 1; d < 64; d <<= 1) s += __shfl_xor(s, d, 64);
    h[node * TK + lane] = hv / s;
}

// ---------------------------------------------------------------------------
// Kernel 2: per-edge composed kernel  K_edge[e,t] = sum_{tau<=t} h_tgt[tau]*h_src[t-tau]
// One wave per edge (4 edges per 256-thread block); lane = t.
// ---------------------------------------------------------------------------
__global__ void kedge_kernel(const float* __restrict__ h,
                             const int* __restrict__ esrc, const int* __restrict__ etgt,
                             float* __restrict__ Ke) {
    __shared__ float s_src[4][TK];
    __shared__ float s_tgt[4][TK];
    int lane = threadIdx.x & 63;
    int grp  = threadIdx.x >> 6;
    int e = blockIdx.x * 4 + grp;
    if (e < EE) {
        int s = esrc[e], t = etgt[e];
        s_src[grp][lane] = h[s * TK + lane];
        s_tgt[grp][lane] = h[t * TK + lane];
    }
    __syncthreads();
    if (e >= EE) return;
    float acc = 0.f;
    for (int tau = 0; tau <= lane; ++tau)
        acc += s_tgt[grp][tau] * s_src[grp][lane - tau];
    Ke[e * TK + lane] = acc;
}

// ---------------------------------------------------------------------------
// Kernel 3: causal 64-tap depthwise conv of one x-row, one block per
// (route, batch).  128 threads, R=16 outputs/thread (covers T=2048).
// LDS swizzle f(i)=i+(i>>4): per-lane stride-16 reads -> stride-17 -> no
// bank conflicts, and ds_read offsets fold to compile-time immediates.
// SELF: plain float4 stores (covers every output once).
// !SELF: atomicAdd into the target row.
// ---------------------------------------------------------------------------
static constexpr int CONV_THREADS = 128;
static constexpr int R = 16;                  // outputs per thread
static constexpr int XS_PHYS = 2244;          // swz(2111)=2242, +2 pad

__device__ __forceinline__ int swz(int i) { return i + (i >> 4); }

template <bool SELF>
__global__ __launch_bounds__(CONV_THREADS)
void conv_kernel(const float* __restrict__ x,
                 const float* __restrict__ h, const float* __restrict__ Ke,
                 const int* __restrict__ esrc, const int* __restrict__ etgt,
                 float* __restrict__ y) {
    __shared__ float xs[XS_PHYS];

    int bid   = blockIdx.x;
    int b     = bid & 1;
    int route = bid >> 1;

    int src, tgt;
    const float* Krow;
    if (SELF) {
        src = route; tgt = route;
        Krow = h + (size_t)route * TK;
    } else {
        src = esrc[route]; tgt = etgt[route];
        Krow = Ke + (size_t)route * TK;
    }

    const float* xrow = x + ((size_t)b * NN + src) * TT;
    int tid = threadIdx.x;

    // zero halo: logical [0,64) holds x[-64..-1] = 0
    if (tid < 64) xs[swz(tid)] = 0.f;

    // stage 2048 floats (512 float4) at logical offset 64
    #pragma unroll
    for (int c = 0; c < 4; ++c) {
        int v = tid + CONV_THREADS * c;       // float4 index
        int i = 64 + 4 * v;                   // logical float index
        float4 val = reinterpret_cast<const float4*>(xrow)[v];
        int p = swz(i);                       // i%16 in {0,4,8,12} -> contiguous 4
        xs[p]     = val.x;
        xs[p + 1] = val.y;
        xs[p + 2] = val.z;
        xs[p + 3] = val.w;
    }
    __syncthreads();

    // K taps: block-uniform -> scalar loads
    float kv[TK];
    #pragma unroll
    for (int i = 0; i < TK; ++i) kv[i] = Krow[i];

    float acc[R];
    #pragma unroll
    for (int r = 0; r < R; ++r) acc[r] = 0.f;

    // thread outputs t0..t0+15, t0 = 16*tid.
    // stream s_j = t0-63+j, logical LDS idx = t0+1+j,
    // physical = 17*tid + (1+j) + ((1+j)>>4)  -> base + compile-time imm.
    const float* xb = xs + 17 * tid;
    #pragma unroll
    for (int j = 0; j < R + TK - 1; ++j) {
        const int cj = (1 + j) + ((1 + j) >> 4);
        float xv = xb[cj];
        #pragma unroll
        for (int r = 0; r < R; ++r) {
            const int tau = r + (TK - 1) - j;
            if (tau >= 0 && tau < TK)
                acc[r] = fmaf(kv[tau], xv, acc[r]);
        }
    }

    float* yrow = y + ((size_t)b * NN + tgt) * TT + R * tid;
    if (SELF) {
        #pragma unroll
        for (int c = 0; c < 4; ++c) {
            float4 v4 = make_float4(acc[4*c], acc[4*c+1], acc[4*c+2], acc[4*c+3]);
            reinterpret_cast<float4*>(yrow)[c] = v4;
        }
    } else {
        #pragma unroll
        for (int r = 0; r < R; ++r) atomicAdd(&yrow[r], acc[r]);
    }
}

// ---------------------------------------------------------------------------
extern "C" void kernel_launch(void* const* d_in, const int* in_sizes, int n_in,
                              void* d_out, int out_size, void* d_ws, size_t ws_size,
                              hipStream_t stream) {
    const float* x      = (const float*)d_in[0];
    const float* params = (const float*)d_in[1];
    const int*   esrc   = (const int*)d_in[2];
    const int*   etgt   = (const int*)d_in[3];
    float* y  = (float*)d_out;

    float* h  = (float*)d_ws;                 // [NN][64]   = 1 MB
    float* Ke = h + (size_t)NN * TK;          // [EE][64]   = 2 MB

    hipLaunchKernelGGL(irf_kernel, dim3(NN * 64 / 256), dim3(256), 0, stream, params, h);
    hipLaunchKernelGGL(kedge_kernel, dim3(EE / 4), dim3(256), 0, stream, h, esrc, etgt, Ke);
    // self routes: write every output exactly once (no zero-init needed)
    hipLaunchKernelGGL((conv_kernel<true>),  dim3(NN * BB), dim3(CONV_THREADS), 0, stream,
                       x, h, Ke, esrc, etgt, y);
    // edge routes: accumulate on top
    hipLaunchKernelGGL((conv_kernel<false>), dim3(EE * BB), dim3(CONV_THREADS), 0, stream,
                       x, h, Ke, esrc, etgt, y);
}

// Round 2
// 104.125 us; speedup vs baseline: 17.6339x; 17.6339x over previous
//
#include <hip/hip_runtime.h>
#include <math.h>

// Problem constants (B=2, N=4096, T=2048, E=8192, MAX_DELAY=64)
static constexpr int NN = 4096;
static constexpr int TT = 2048;
static constexpr int EE = 8192;
static constexpr int BB = 2;
static constexpr int TK = 64;

// ---------------------------------------------------------------------------
// Kernel 1: per-node IRF  h[n,tau] = exp(-tau/kst)/kst, normalized over tau.
// ---------------------------------------------------------------------------
__global__ void irf_kernel(const float* __restrict__ params, float* __restrict__ h) {
    int t = blockIdx.x * blockDim.x + threadIdx.x;
    int node = t >> 6, lane = t & 63;
    if (node >= NN) return;
    float p = params[node * 2];
    float sp = fmaxf(p, 0.f) + log1pf(expf(-fabsf(p)));       // stable softplus
    float kst = sp + 0.1f;
    float inv = 1.0f / kst;
    float hv = expf(-(float)lane * inv) * inv;
    float s = hv;
    #pragma unroll
    for (int d = 1; d < 64; d <<= 1) s += __shfl_xor(s, d, 64);
    h[node * TK + lane] = hv / s;
}

// ---------------------------------------------------------------------------
// Kernel 2: per-edge composed kernel (truncated to 64 taps, like reference)
// ---------------------------------------------------------------------------
__global__ void kedge_kernel(const float* __restrict__ h,
                             const int* __restrict__ esrc, const int* __restrict__ etgt,
                             float* __restrict__ Ke) {
    __shared__ float s_src[4][TK];
    __shared__ float s_tgt[4][TK];
    int lane = threadIdx.x & 63;
    int grp  = threadIdx.x >> 6;
    int e = blockIdx.x * 4 + grp;
    if (e < EE) {
        int s = esrc[e], t = etgt[e];
        s_src[grp][lane] = h[s * TK + lane];
        s_tgt[grp][lane] = h[t * TK + lane];
    }
    __syncthreads();
    if (e >= EE) return;
    float acc = 0.f;
    for (int tau = 0; tau <= lane; ++tau)
        acc += s_tgt[grp][tau] * s_src[grp][lane - tau];
    Ke[e * TK + lane] = acc;
}

// ---------------------------------------------------------------------------
// CSR build: cnt -> scan -> scatter   (all trivial-cost)
// ---------------------------------------------------------------------------
__global__ void zero_kernel(int* __restrict__ p, int n) {
    int i = blockIdx.x * blockDim.x + threadIdx.x;
    if (i < n) p[i] = 0;
}

__global__ void count_kernel(const int* __restrict__ etgt, int* __restrict__ cnt) {
    int e = blockIdx.x * blockDim.x + threadIdx.x;
    if (e < EE) atomicAdd(&cnt[etgt[e]], 1);
}

// single block, 1024 threads, exclusive scan of 4096 ints
__global__ void scan_kernel(const int* __restrict__ cnt, int* __restrict__ rowstart) {
    __shared__ int sc[1024];
    int t = threadIdx.x;
    int4 v = reinterpret_cast<const int4*>(cnt)[t];
    int s0 = v.x, s1 = s0 + v.y, s2 = s1 + v.z, s3 = s2 + v.w;
    sc[t] = s3;
    __syncthreads();
    for (int off = 1; off < 1024; off <<= 1) {
        int add = (t >= off) ? sc[t - off] : 0;
        __syncthreads();
        sc[t] += add;
        __syncthreads();
    }
    int excl = sc[t] - s3;
    int4 o;
    o.x = excl; o.y = excl + s0; o.z = excl + s1; o.w = excl + s2;
    reinterpret_cast<int4*>(rowstart)[t] = o;
}

__global__ void scatter_kernel(const int* __restrict__ etgt,
                               const int* __restrict__ rowstart,
                               int* __restrict__ cursor, int* __restrict__ elist) {
    int e = blockIdx.x * blockDim.x + threadIdx.x;
    if (e < EE) {
        int t = etgt[e];
        int pos = atomicAdd(&cursor[t], 1);
        elist[rowstart[t] + pos] = e;
    }
}

// ---------------------------------------------------------------------------
// Kernel 3: gather-conv. One block per (tgt, batch); block owns its output
// row exclusively -> plain float4 stores, ZERO atomics.
// LDS swizzle f(i)=i+(i>>4): per-lane stride-16 reads -> stride-17 ->
// conflict-free, ds_read offsets fold to compile-time immediates.
// ---------------------------------------------------------------------------
static constexpr int CONV_THREADS = 128;
static constexpr int R = 16;                  // outputs per thread
static constexpr int XS_PHYS = 2244;          // swz(2111)=2242, +2 pad

__device__ __forceinline__ int swz(int i) { return i + (i >> 4); }

__device__ __forceinline__ void stage_row(float* __restrict__ xs,
                                          const float* __restrict__ xrow, int tid) {
    #pragma unroll
    for (int c = 0; c < 4; ++c) {
        int v = tid + CONV_THREADS * c;       // float4 index
        int i = 64 + 4 * v;                   // logical float index
        float4 val = reinterpret_cast<const float4*>(xrow)[v];
        int p = swz(i);                       // i%16 in {0,4,8,12} -> contiguous 4
        xs[p]     = val.x;
        xs[p + 1] = val.y;
        xs[p + 2] = val.z;
        xs[p + 3] = val.w;
    }
}

__device__ __forceinline__ void conv_accum(const float* __restrict__ xs,
                                           const float* __restrict__ Krow,
                                           float acc[R], int tid) {
    float kv[TK];
    #pragma unroll
    for (int i = 0; i < TK; ++i) kv[i] = Krow[i];   // uniform -> SGPRs
    const float* xb = xs + 17 * tid;
    #pragma unroll
    for (int j = 0; j < R + TK - 1; ++j) {
        const int cj = (1 + j) + ((1 + j) >> 4);    // compile-time imm offset
        float xv = xb[cj];
        #pragma unroll
        for (int r = 0; r < R; ++r) {
            const int tau = r + (TK - 1) - j;
            if (tau >= 0 && tau < TK)
                acc[r] = fmaf(kv[tau], xv, acc[r]);
        }
    }
}

__global__ __launch_bounds__(CONV_THREADS)
void conv_gather_kernel(const float* __restrict__ x,
                        const float* __restrict__ h, const float* __restrict__ Ke,
                        const int* __restrict__ esrc,
                        const int* __restrict__ elist,
                        const int* __restrict__ rowstart,
                        const int* __restrict__ cnt,
                        float* __restrict__ y) {
    __shared__ float xs[XS_PHYS];

    int bid = blockIdx.x;
    int b   = bid & 1;
    int tgt = bid >> 1;
    int tid = threadIdx.x;

    // zero halo: logical [0,64) = x[-64..-1] = 0 (persists across routes)
    if (tid < 64) xs[swz(tid)] = 0.f;

    // ---- self route ----
    stage_row(xs, x + ((size_t)b * NN + tgt) * TT, tid);
    __syncthreads();

    float acc[R];
    #pragma unroll
    for (int r = 0; r < R; ++r) acc[r] = 0.f;
    conv_accum(xs, h + (size_t)tgt * TK, acc, tid);

    // ---- incoming edges ----
    int start = rowstart[tgt];
    int deg   = cnt[tgt];
    for (int i = 0; i < deg; ++i) {
        int e = elist[start + i];
        e = __builtin_amdgcn_readfirstlane(e);
        int src = esrc[e];
        src = __builtin_amdgcn_readfirstlane(src);
        __syncthreads();                       // previous compute done reading xs
        stage_row(xs, x + ((size_t)b * NN + src) * TT, tid);
        __syncthreads();
        conv_accum(xs, Ke + (size_t)e * TK, acc, tid);
    }

    float* yrow = y + ((size_t)b * NN + tgt) * TT + R * tid;
    #pragma unroll
    for (int c = 0; c < 4; ++c)
        reinterpret_cast<float4*>(yrow)[c] =
            make_float4(acc[4*c], acc[4*c+1], acc[4*c+2], acc[4*c+3]);
}

// ---------------------------------------------------------------------------
extern "C" void kernel_launch(void* const* d_in, const int* in_sizes, int n_in,
                              void* d_out, int out_size, void* d_ws, size_t ws_size,
                              hipStream_t stream) {
    const float* x      = (const float*)d_in[0];
    const float* params = (const float*)d_in[1];
    const int*   esrc   = (const int*)d_in[2];
    const int*   etgt   = (const int*)d_in[3];
    float* y = (float*)d_out;

    float* h  = (float*)d_ws;                      // [NN][64]  1 MB
    float* Ke = h + (size_t)NN * TK;               // [EE][64]  2 MB
    int* cnt      = (int*)(Ke + (size_t)EE * TK);  // [NN]
    int* cursor   = cnt + NN;                      // [NN]
    int* rowstart = cursor + NN;                   // [NN]
    int* elist    = rowstart + NN;                 // [EE]

    hipLaunchKernelGGL(irf_kernel, dim3(NN * 64 / 256), dim3(256), 0, stream, params, h);
    hipLaunchKernelGGL(kedge_kernel, dim3(EE / 4), dim3(256), 0, stream, h, esrc, etgt, Ke);

    hipLaunchKernelGGL(zero_kernel, dim3((2 * NN + 255) / 256), dim3(256), 0, stream, cnt, 2 * NN);
    hipLaunchKernelGGL(count_kernel, dim3(EE / 256), dim3(256), 0, stream, etgt, cnt);
    hipLaunchKernelGGL(scan_kernel, dim3(1), dim3(1024), 0, stream, cnt, rowstart);
    hipLaunchKernelGGL(scatter_kernel, dim3(EE / 256), dim3(256), 0, stream, etgt, rowstart, cursor, elist);

    hipLaunchKernelGGL(conv_gather_kernel, dim3(NN * BB), dim3(CONV_THREADS), 0, stream,
                       x, h, Ke, esrc, elist, rowstart, cnt, y);
}

// Round 3
// 65.148 us; speedup vs baseline: 28.1838x; 1.5983x over previous
//
#include <hip/hip_runtime.h>
#include <math.h>

// Problem constants (B=2, N=4096, T=2048, E=8192, MAX_DELAY=64)
static constexpr int NN = 4096;
static constexpr int TT = 2048;
static constexpr int EE = 8192;
static constexpr int TK = 64;

typedef __attribute__((ext_vector_type(8))) short   short8v;  // 8 bf16 = 4 VGPR
typedef __attribute__((ext_vector_type(4))) float   float4v;  // MFMA acc

__device__ __forceinline__ unsigned short f2bf(float f) {     // fp32 -> bf16 RNE
    union { float f; unsigned u; } v; v.f = f;
    unsigned r = v.u + 0x7fffu + ((v.u >> 16) & 1u);
    return (unsigned short)(r >> 16);
}

// ---------------------------------------------------------------------------
// K1: per-node IRF (1024 blocks) + zero cnt (16 blocks)
// ---------------------------------------------------------------------------
__global__ void irf_zero_kernel(const float* __restrict__ params,
                                float* __restrict__ hirf, int* __restrict__ cnt) {
    int blk = blockIdx.x;
    if (blk < 1024) {
        int t = blk * 256 + threadIdx.x;
        int node = t >> 6, lane = t & 63;
        float p = params[node * 2];
        float sp = fmaxf(p, 0.f) + log1pf(expf(-fabsf(p)));   // stable softplus
        float kst = sp + 0.1f;
        float inv = 1.0f / kst;
        float hv = expf(-(float)lane * inv) * inv;
        float s = hv;
        #pragma unroll
        for (int d = 1; d < 64; d <<= 1) s += __shfl_xor(s, d, 64);
        hirf[node * TK + lane] = hv / s;
    } else {
        int i = (blk - 1024) * 256 + threadIdx.x;
        if (i < NN) cnt[i] = 0;
    }
}

// ---------------------------------------------------------------------------
// K2: per-edge composed kernel (4 edges / 256-thr block) + degree count
// ---------------------------------------------------------------------------
__global__ void kedge_count_kernel(const float* __restrict__ hirf,
                                   const int* __restrict__ esrc, const int* __restrict__ etgt,
                                   float* __restrict__ Ke, int* __restrict__ cnt) {
    __shared__ float s_src[4][TK];
    __shared__ float s_tgt[4][TK];
    int lane = threadIdx.x & 63;
    int grp  = threadIdx.x >> 6;
    int e = blockIdx.x * 4 + grp;
    int s = esrc[e], t = etgt[e];
    s_src[grp][lane] = hirf[s * TK + lane];
    s_tgt[grp][lane] = hirf[t * TK + lane];
    __syncthreads();
    float acc = 0.f;
    for (int tau = 0; tau <= lane; ++tau)
        acc += s_tgt[grp][tau] * s_src[grp][lane - tau];
    Ke[e * TK + lane] = acc;
    if (lane == 0) atomicAdd(&cnt[t], 1);
}

// ---------------------------------------------------------------------------
// K3: single-block exclusive scan of cnt + CSR scatter (LDS cursors)
// ---------------------------------------------------------------------------
__global__ __launch_bounds__(1024)
void scan_scatter_kernel(const int* __restrict__ cnt, int* __restrict__ rowstart,
                         const int* __restrict__ etgt, int* __restrict__ elist) {
    __shared__ int sc[1024];
    __shared__ int scur[NN];
    int t = threadIdx.x;
    int4 v = reinterpret_cast<const int4*>(cnt)[t];
    int s0 = v.x, s1 = s0 + v.y, s2 = s1 + v.z, s3 = s2 + v.w;
    sc[t] = s3;
    __syncthreads();
    for (int off = 1; off < 1024; off <<= 1) {
        int add = (t >= off) ? sc[t - off] : 0;
        __syncthreads();
        sc[t] += add;
        __syncthreads();
    }
    int excl = sc[t] - s3;
    int4 o; o.x = excl; o.y = excl + s0; o.z = excl + s1; o.w = excl + s2;
    reinterpret_cast<int4*>(rowstart)[t] = o;
    reinterpret_cast<int4*>(scur)[t] = o;       // LDS cursors start at rowstart
    __syncthreads();
    for (int e = t; e < EE; e += 1024) {
        int tg = etgt[e];
        int pos = atomicAdd(&scur[tg], 1);
        elist[pos] = e;
    }
}

// ---------------------------------------------------------------------------
// K4: polyphase MFMA conv.  One block per target; 256 thr = 4 waves,
// wave = (batch, half-of-time).  Routes (self + incoming edges) iterate with
// double-buffered LDS {x-rows bf16, K-Toeplitz table} and reg prefetch.
//
//   y[16a+r] = sum_{delta,p} C[r][16*delta+p] * x[16*(a-delta)+p]
//   C[r][16*delta+p] = K_clip[r - p + 16*delta]     (zero outside [0,64))
//
// MFMA 16x16x32_bf16: A = C-chunk [16 x 32], B = x-chunk [32 x 16 a-blocks].
// Per-lane k-convention kappa = 8h+j (h=lane>>4) used consistently for A and
// B; contraction is invariant to the true hw k-permutation.  K-dim = 96 =
// 3 chunks; delta=5 half is zeroed via the table.
// ---------------------------------------------------------------------------
static constexpr int HALO = 80;                 // covers delta<=5 lookback
static constexpr int XLEN = HALO + TT;          // 2128 bf16 per batch-row
static constexpr int TABS = 96;                 // table row stride (16B align)
static constexpr int TABE = TABS * 16;          // 1536

struct __align__(16) ConvBuf {
    unsigned short x[2][XLEN];                  // [batch][time(+halo)]
    unsigned short tab[TABE];                   // Krev_r[c]: [r][80 + c]
};

__global__ __launch_bounds__(256)
void conv_mfma_kernel(const float* __restrict__ x,
                      const float* __restrict__ hirf, const float* __restrict__ Ke,
                      const int* __restrict__ esrc,
                      const int* __restrict__ elist,
                      const int* __restrict__ rowstart,
                      const int* __restrict__ cnt,
                      float* __restrict__ y) {
    __shared__ ConvBuf sbuf[2];

    const int tid = threadIdx.x;
    const int tgt = blockIdx.x;
    const int start = rowstart[tgt];
    const int nroutes = cnt[tgt] + 1;

    const int l      = tid & 63;
    const int lane16 = l & 15;
    const int h      = l >> 4;        // 0..3
    const int hlo    = h & 1, hhi = h >> 1;
    const int wv     = tid >> 6;
    const int bsel   = wv >> 1;       // batch
    const int half   = wv & 1;        // time half

    // zero halos of both buffers/batches (done once)
    for (int idx = tid; idx < 2 * 2 * HALO; idx += 256) {
        int nb = idx / (2 * HALO), rem = idx % (2 * HALO);
        sbuf[nb].x[rem / HALO][rem % HALO] = 0;
    }

    float4v acc[4];
    #pragma unroll
    for (int T = 0; T < 4; ++T) acc[T] = (float4v){0.f, 0.f, 0.f, 0.f};

    float4 px[4]; float pk;
    auto LOADR = [&](int src, const float* Kp) {
        const float4* r0 = reinterpret_cast<const float4*>(x + (size_t)src * TT);
        const float4* r1 = reinterpret_cast<const float4*>(x + ((size_t)NN + src) * TT);
        px[0] = r0[tid]; px[1] = r0[tid + 256];
        px[2] = r1[tid]; px[3] = r1[tid + 256];
        pk = Kp[tid & 63];
    };
    auto WRITE = [&](int nb) {
        #pragma unroll
        for (int c = 0; c < 4; ++c) {
            int bb = c >> 1;
            int u  = (c & 1) ? tid + 256 : tid;
            unsigned lo = (unsigned)f2bf(px[c].x) | ((unsigned)f2bf(px[c].y) << 16);
            unsigned hi = (unsigned)f2bf(px[c].z) | ((unsigned)f2bf(px[c].w) << 16);
            *reinterpret_cast<uint2*>(&sbuf[nb].x[bb][HALO + 4 * u]) = make_uint2(lo, hi);
        }
        unsigned short kb = f2bf(pk);
        int i = tid & 63, rg = tid >> 6;
        #pragma unroll
        for (int rr = 0; rr < 4; ++rr) {
            int r = rg * 4 + rr;
            sbuf[nb].tab[TABS * r + 80 + r - i] = kb;      // value entries c=r-i
        }
        int r2 = tid >> 4, z = tid & 15;                   // 32 zero entries/row
        sbuf[nb].tab[TABS * r2 + z] = 0;
        sbuf[nb].tab[TABS * r2 + ((z <= r2) ? z + 16 : 80 + z)] = 0;
    };
    auto COMPUTE = [&](int cb) {
        const unsigned short* tab = sbuf[cb].tab;
        const unsigned short* xb  = sbuf[cb].x[bsel];
        const int abase = TABS * lane16 + 80 + 8 * hlo;
        short8v A0 = *reinterpret_cast<const short8v*>(&tab[abase - 16 * (0 + hhi)]);
        short8v A1 = *reinterpret_cast<const short8v*>(&tab[abase - 16 * (2 + hhi)]);
        short8v A2 = *reinterpret_cast<const short8v*>(&tab[abase - 16 * (4 + hhi)]);
        #pragma unroll
        for (int T = 0; T < 4; ++T) {
            int bb = HALO + 16 * (64 * half + 16 * T + lane16) + 8 * hlo;
            short8v B0 = *reinterpret_cast<const short8v*>(&xb[bb - 16 * (0 + hhi)]);
            acc[T] = __builtin_amdgcn_mfma_f32_16x16x32_bf16(A0, B0, acc[T], 0, 0, 0);
            short8v B1 = *reinterpret_cast<const short8v*>(&xb[bb - 16 * (2 + hhi)]);
            acc[T] = __builtin_amdgcn_mfma_f32_16x16x32_bf16(A1, B1, acc[T], 0, 0, 0);
            short8v B2 = *reinterpret_cast<const short8v*>(&xb[bb - 16 * (4 + hhi)]);
            acc[T] = __builtin_amdgcn_mfma_f32_16x16x32_bf16(A2, B2, acc[T], 0, 0, 0);
        }
    };

    // prologue: route 0 = self
    LOADR(tgt, hirf + (size_t)tgt * TK);
    WRITE(0);
    int eN = 0, srcN = 0;
    if (nroutes > 1) { eN = elist[start]; srcN = esrc[eN]; }
    __syncthreads();

    int cur = 0;
    for (int i = 0; i < nroutes; ++i) {
        if (i + 1 < nroutes) {
            LOADR(srcN, Ke + (size_t)eN * TK);            // prefetch route i+1
            if (i + 2 < nroutes) { eN = elist[start + i + 1]; srcN = esrc[eN]; }
        }
        COMPUTE(cur);
        if (i + 1 < nroutes) {
            WRITE(cur ^ 1);
            __syncthreads();
            cur ^= 1;
        }
    }

    float* yrow = y + ((size_t)bsel * NN + tgt) * TT;
    #pragma unroll
    for (int T = 0; T < 4; ++T) {
        int tb = 16 * (64 * half + 16 * T + lane16) + 4 * h;
        #pragma unroll
        for (int e = 0; e < 4; ++e) yrow[tb + e] = acc[T][e];
    }
}

// ---------------------------------------------------------------------------
extern "C" void kernel_launch(void* const* d_in, const int* in_sizes, int n_in,
                              void* d_out, int out_size, void* d_ws, size_t ws_size,
                              hipStream_t stream) {
    const float* x      = (const float*)d_in[0];
    const float* params = (const float*)d_in[1];
    const int*   esrc   = (const int*)d_in[2];
    const int*   etgt   = (const int*)d_in[3];
    float* y = (float*)d_out;

    float* hirf = (float*)d_ws;                        // [NN][64]
    float* Ke   = hirf + (size_t)NN * TK;              // [EE][64]
    int* cnt      = (int*)(Ke + (size_t)EE * TK);      // [NN]
    int* rowstart = cnt + NN;                          // [NN]
    int* elist    = rowstart + NN;                     // [EE]

    hipLaunchKernelGGL(irf_zero_kernel, dim3(1040), dim3(256), 0, stream, params, hirf, cnt);
    hipLaunchKernelGGL(kedge_count_kernel, dim3(EE / 4), dim3(256), 0, stream,
                       hirf, esrc, etgt, Ke, cnt);
    hipLaunchKernelGGL(scan_scatter_kernel, dim3(1), dim3(1024), 0, stream,
                       cnt, rowstart, etgt, elist);
    hipLaunchKernelGGL(conv_mfma_kernel, dim3(NN), dim3(256), 0, stream,
                       x, hirf, Ke, esrc, elist, rowstart, cnt, y);
}